// Round 19
// baseline (80.852 us; speedup 1.0000x reference)
//
#include <hip/hip_runtime.h>

#define N_ 256
#define L_ 4096
#define DM_ 2048
#define STEPF (1.0f / 4096.0f)
#define NW 10
#define NV 5
#define RQN 4608

typedef short bf16x8 __attribute__((ext_vector_type(8)));
typedef float f32x4 __attribute__((ext_vector_type(4)));
typedef float f32x16 __attribute__((ext_vector_type(16)));
typedef unsigned int uint32;

__device__ __forceinline__ uint32 bf16rne(float f) {
    uint32 u = __builtin_bit_cast(uint32, f);
    return (u + 0x7FFFu + ((u >> 16) & 1u)) >> 16;
}
__device__ __forceinline__ float rdlane(float v, int l) {
    return __builtin_bit_cast(float, __builtin_amdgcn_readlane(__builtin_bit_cast(int, v), l));
}
__device__ __forceinline__ float hif(float x) {
    return __builtin_bit_cast(float, __builtin_bit_cast(uint32, x) & 0xFFFF0000u);
}
#define PK2(LO, HI) __builtin_amdgcn_perm(__builtin_bit_cast(uint32, (HI)), \
                                          __builtin_bit_cast(uint32, (LO)), 0x07060302u)

// ---------------- Phase 1: build K (block 0) + pack y->bf16 (blocks 1..256) ----------------
// (bit-identical to R17's kernel)
__global__ __launch_bounds__(1024) void k_build(const float* __restrict__ Araw,
                                                const float* __restrict__ Bv,
                                                const float* __restrict__ Cv,
                                                const float* __restrict__ yf,
                                                uint2* __restrict__ Rqg,
                                                uint4* __restrict__ ybf) {
    const int tid = threadIdx.x;
    if (blockIdx.x > 0) {
        const size_t base = (size_t)(blockIdx.x - 1) * 32768;
        const float4* yin = (const float4*)(yf + base);
        uint4* yo = ybf + base / 8;
#pragma unroll
        for (int i = 0; i < 4; ++i) {
            int c = i * 1024 + tid;
            float4 q0 = yin[2 * c], q1 = yin[2 * c + 1];
            uint4 o; o.x = PK2(q0.x, q0.y); o.y = PK2(q0.z, q0.w);
                     o.z = PK2(q1.x, q1.y); o.w = PK2(q1.z, q1.w);
            yo[c] = o;
        }
        return;
    }

    __shared__ float sm[39168];
    float* kry = sm;
    float* red = sm + 3840;
    float* Wl  = sm + 5888;
    float* Vt  = sm + 22528;
    float* Kf  = sm;

    const int j = tid & 255, seg = tid >> 8, lane = tid & 63;
    const int e = 64 * seg + lane;
    float a[64];

#define DOT64(S0, S1, VV) { \
    _Pragma("unroll") \
    for (int m = 0; m < 64; m += 2) { \
        S0 = fmaf(rdlane(VV, m), a[m], S0); \
        S1 = fmaf(rdlane(VV, m + 1), a[m + 1], S1); \
    } }

#pragma unroll
    for (int m = 0; m < 64; ++m) a[m] = Araw[(64 * seg + m) * 256 + j];
    if (tid < 256) kry[tid] = Cv[tid];
    __syncthreads();
    const float WSC = 4032.0f / 4096.0f;
    {
        float vv = kry[e];
        for (int n = 1; n < NW; ++n) {
            float s0 = 0.f, s1 = 0.f;
            DOT64(s0, s1, vv)
            float* rb = red + (n & 1) * 1024;
            rb[seg * 256 + j] = s0 + s1;
            __syncthreads();
            float sc = WSC / (float)n;
            vv = (rb[e] + rb[256 + e] + rb[512 + e] + rb[768 + e]) * sc;
            if (tid < 256)
                kry[n * 256 + tid] = (rb[tid] + rb[256 + tid] + rb[512 + tid] + rb[768 + tid]) * sc;
        }
    }
    __syncthreads();
    {
        float kj[NW];
#pragma unroll
        for (int n = 0; n < NW; ++n) kj[n] = kry[n * 256 + j];
#pragma unroll
        for (int u = 0; u < 16; ++u) {
            int q = seg + 4 * u;
            float c = (float)q * (1.0f / 63.0f);
            float h = kj[NW - 1];
#pragma unroll
            for (int n = NW - 2; n >= 0; --n) h = fmaf(c, h, kj[n]);
            Wl[q * 260 + j] = h;
        }
    }
    {
        const float4* Ar = (const float4*)(Araw + (size_t)j * 256 + 64 * seg);
#pragma unroll
        for (int m4 = 0; m4 < 16; ++m4) {
            float4 q4 = Ar[m4];
            a[4 * m4] = q4.x; a[4 * m4 + 1] = q4.y; a[4 * m4 + 2] = q4.z; a[4 * m4 + 3] = q4.w;
        }
    }
    const float ms = 0.5f * STEPF;
    const float bve = Bv[e];
    {
        float vv = bve;
        for (int it = 0; it < 2; ++it) {
            float s0 = 0.f, s1 = 0.f;
            DOT64(s0, s1, vv)
            float* rb = red + (it & 1) * 1024;
            rb[seg * 256 + j] = s0 + s1;
            __syncthreads();
            vv = fmaf(ms, rb[e] + rb[256 + e] + rb[512 + e] + rb[768 + e], bve);
            if (it == 1 && tid < 256) {
                float su = rb[tid] + rb[256 + tid] + rb[512 + tid] + rb[768 + tid];
                kry[tid] = STEPF * fmaf(ms, su, Bv[tid]);
            }
        }
    }
    __syncthreads();
    const float VSC = 63.0f / 4096.0f;
    {
        float vv = kry[e];
        for (int n = 1; n < NV; ++n) {
            float s0 = 0.f, s1 = 0.f;
            DOT64(s0, s1, vv)
            float* rb = red + (n & 1) * 1024;
            rb[seg * 256 + j] = s0 + s1;
            __syncthreads();
            float sc = VSC / (float)n;
            vv = (rb[e] + rb[256 + e] + rb[512 + e] + rb[768 + e]) * sc;
            if (tid < 256)
                kry[n * 256 + tid] = (rb[tid] + rb[256 + tid] + rb[512 + tid] + rb[768 + tid]) * sc;
        }
    }
    __syncthreads();
    {
        float kj[NV];
#pragma unroll
        for (int n = 0; n < NV; ++n) kj[n] = kry[n * 256 + j];
#pragma unroll
        for (int u = 0; u < 16; ++u) {
            int r = seg + 4 * u;
            float c = (float)r * (1.0f / 63.0f);
            float h = kj[NV - 1];
#pragma unroll
            for (int n = NV - 2; n >= 0; --n) h = fmaf(c, h, kj[n]);
            Vt[r * 260 + j] = h;
        }
    }
    __syncthreads();
    {
        const int wv = tid >> 6;
        const int qt = wv >> 2, rt = wv & 3;
        const int n16 = lane & 15, g4 = lane >> 4;
        const int q = 16 * qt + n16;
        const int r = 16 * rt + n16;
        f32x4 ac = (f32x4){0.f, 0.f, 0.f, 0.f};
        for (int s = 0; s < 8; ++s) {
            const int kk = 32 * s + 8 * g4;
            float4 w0 = *(const float4*)&Wl[q * 260 + kk];
            float4 w1 = *(const float4*)&Wl[q * 260 + kk + 4];
            float4 v0 = *(const float4*)&Vt[r * 260 + kk];
            float4 v1 = *(const float4*)&Vt[r * 260 + kk + 4];
            uint4 uh; uh.x = PK2(w0.x, w0.y); uh.y = PK2(w0.z, w0.w);
                      uh.z = PK2(w1.x, w1.y); uh.w = PK2(w1.z, w1.w);
            float l0 = w0.x - hif(w0.x), l1 = w0.y - hif(w0.y);
            float l2 = w0.z - hif(w0.z), l3 = w0.w - hif(w0.w);
            float l4 = w1.x - hif(w1.x), l5 = w1.y - hif(w1.y);
            float l6 = w1.z - hif(w1.z), l7 = w1.w - hif(w1.w);
            uint4 ul; ul.x = PK2(l0, l1); ul.y = PK2(l2, l3);
                      ul.z = PK2(l4, l5); ul.w = PK2(l6, l7);
            uint4 uv; uv.x = PK2(v0.x, v0.y); uv.y = PK2(v0.z, v0.w);
                      uv.z = PK2(v1.x, v1.y); uv.w = PK2(v1.z, v1.w);
            ac = __builtin_amdgcn_mfma_f32_16x16x32_bf16(__builtin_bit_cast(bf16x8, uh),
                                                         __builtin_bit_cast(bf16x8, uv), ac, 0, 0, 0);
            ac = __builtin_amdgcn_mfma_f32_16x16x32_bf16(__builtin_bit_cast(bf16x8, ul),
                                                         __builtin_bit_cast(bf16x8, uv), ac, 0, 0, 0);
        }
#pragma unroll
        for (int jj = 0; jj < 4; ++jj)
            Kf[(16 * qt + 4 * g4 + jj) * 64 + r] = ac[jj];
    }
    __syncthreads();
    for (int i = tid; i < RQN; i += 1024) {
        int aa = 4095 - i;
        uint32 e0 = (aa >= 0) ? bf16rne(Kf[aa]) : 0u;
        uint32 e1 = (aa >= 1) ? bf16rne(Kf[aa - 1]) : 0u;
        uint32 e2 = (aa >= 2) ? bf16rne(Kf[aa - 2]) : 0u;
        uint32 e3 = (aa >= 3) ? bf16rne(Kf[aa - 3]) : 0u;
        uint2 v; v.x = e0 | (e1 << 16); v.y = e2 | (e3 << 16);
        Rqg[i] = v;
    }
#undef DOT64
}

// ---------------- Phase 2: MFMA causal conv, 32x32x16 (4x work per MFMA instr) ----------------
// Cross-round law: per-wave step cost ~ const * #MFMA-instrs (50-85 cyc/instr, waves serialize).
// Counter: 4x bigger MFMAs.  D[m=t][n=d] = sum_k A[t][k] B[k][d]:
//   A = Toeplitz K (LDS quad table, per-lane 8 consecutive rev -> 2x b64;
//       rotation frag(tt,s+2)=frag(tt-1,s) -> 1 new A-frag/step),
//   B = y bf16 (ONE dwordx4/step, shared by all 4 MFMAs).
// T=4 tiles (128-col strips, 32 strips), pairs (31-by,by) -> 132 steps/wave const; j-split 2.
// Block = 4 waves (ds2 x jh2), 64 d-rows; grid (32,16) = 512 blocks = 2/CU.
__global__ __launch_bounds__(256, 2) void k_conv(const uint2* __restrict__ Rqg,
                                                 const uint4* __restrict__ ybf,
                                                 const float* __restrict__ y,
                                                 const float* __restrict__ Dp,
                                                 float* __restrict__ out) {
    __shared__ uint2 Rq[RQN];
    __shared__ f32x4 mbuf[2][8][64];
    const int tid = threadIdx.x;
#pragma unroll
    for (int i = 0; i < RQN / 256; ++i) Rq[i * 256 + tid] = Rqg[i * 256 + tid];
    __syncthreads();

    const int w = tid >> 6, lane = tid & 63;
    const int m32 = lane & 31, h = lane >> 5;
    const int ds = w & 1, jh = w >> 1;
    const int by = (int)blockIdx.y;                   // 0..15
    const int d0w = (int)blockIdx.x * 64 + ds * 32;
    const int d = d0w + m32;
    const uint4* __restrict__ ybr = ybf + (size_t)d * (L_ / 8);
    const float D0 = Dp[0];

#define LOADF(SL, I0) { \
    uint2 u0 = Rq[(I0)]; uint2 u1 = Rq[(I0) + 4]; \
    uint4 uu; uu.x = u0.x; uu.y = u0.y; uu.z = u1.x; uu.w = u1.y; \
    fr[SL] = __builtin_bit_cast(bf16x8, uu); }
#define MFT(TT, SL) acc[TT] = __builtin_amdgcn_mfma_f32_32x32x16_bf16(fr[SL], bv, acc[TT], 0, 0, 0);

// E-step phase P (local even s = 2*P'): tt uses slot (P-tt)&3; tt=3's slot (P+1)&3 is
// consumed first then refilled with next-E's tt=0 frag.  O-steps use slots 4..7.
#define STEPE(P) { \
    bv = __builtin_bit_cast(bf16x8, ave); \
    MFT(3, ((P) + 1) & 3) \
    LOADF(((P) + 1) & 3, bcurE) bcurE += 32; \
    ave = ybr[yn & 511]; yn += 2; \
    MFT(0, (P) & 3) MFT(1, ((P) + 3) & 3) MFT(2, ((P) + 2) & 3) \
}
#define STEPO(P) { \
    bv = __builtin_bit_cast(bf16x8, avo); \
    MFT(3, 4 + (((P) + 1) & 3)) \
    LOADF(4 + (((P) + 1) & 3), bcurO) bcurO += 32; \
    avo = ybr[yn & 511]; yn += 2; \
    MFT(0, 4 + ((P) & 3)) MFT(1, 4 + (((P) + 3) & 3)) MFT(2, 4 + (((P) + 2) & 3)) \
}

#define ROUND8() \
    STEPE(0) STEPO(0) STEPE(1) STEPO(1) STEPE(2) STEPO(2) STEPE(3) STEPO(3)
#define REM4() \
    STEPE(0) STEPO(0) STEPE(1) STEPO(1)

    for (int strip = 0; strip < 2; ++strip) {
        const int v = strip ? by : (31 - by);
        const int t0 = v << 7;
        const int Sh = 2 * (v + 1);       // per-wave s-steps of K=16... (total S = 8v+8; half = 4v+4)
        const int ShW = 4 * (v + 1);      // per-wave steps
        const int s0 = jh * ShW;          // starting K=16 chunk
        (void)Sh;

        f32x16 acc[4] = {};
        bf16x8 fr[8], bv;
        uint4 ave, avo;

        const int IB = 4095 - t0 - m32 + 8 * h + 16 * s0;
        LOADF(0, IB)      LOADF(3, IB - 32) LOADF(2, IB - 64) LOADF(1, IB - 96)
        LOADF(4, IB + 16) LOADF(7, IB - 16) LOADF(6, IB - 48) LOADF(5, IB - 80)
        ave = ybr[(2 * s0 + h) & 511];
        avo = ybr[(2 * s0 + 2 + h) & 511];
        int bcurE = IB + 32, bcurO = IB + 48;
        int yn = 2 * s0 + 4 + h;

        const int n8 = ShW >> 3;
        for (int it = 0; it < n8; ++it) {
            ROUND8()
        }
        if (ShW & 4) {
            REM4()
        }

        // ---- merge j-halves (2 LDS rounds of 2 tiles), then jh=0 stores ----
#pragma unroll
        for (int rr = 0; rr < 2; ++rr) {
            if (jh == 1) {
#pragma unroll
                for (int tp = 0; tp < 2; ++tp)
#pragma unroll
                    for (int c = 0; c < 4; ++c) {
                        f32x4 ch = {acc[2 * rr + tp][4 * c], acc[2 * rr + tp][4 * c + 1],
                                    acc[2 * rr + tp][4 * c + 2], acc[2 * rr + tp][4 * c + 3]};
                        mbuf[ds][4 * tp + c][lane] = ch;
                    }
            }
            __syncthreads();
            if (jh == 0) {
#pragma unroll
                for (int tp = 0; tp < 2; ++tp)
#pragma unroll
                    for (int c = 0; c < 4; ++c) {
                        f32x4 mm = mbuf[ds][4 * tp + c][lane];
                        acc[2 * rr + tp][4 * c]     += mm[0];
                        acc[2 * rr + tp][4 * c + 1] += mm[1];
                        acc[2 * rr + tp][4 * c + 2] += mm[2];
                        acc[2 * rr + tp][4 * c + 3] += mm[3];
                    }
            }
            __syncthreads();
        }
        if (jh == 0) {
            // C/D: col = lane&31 -> d; row = (r&3) + 8*(r>>2) + 4*h -> t offset.
#pragma unroll
            for (int tt = 0; tt < 4; ++tt) {
#pragma unroll
                for (int q = 0; q < 4; ++q) {
                    int tb = t0 + 32 * tt + 8 * q + 4 * h;
                    size_t ix = (size_t)d * L_ + tb;
                    float4 yv = *(const float4*)&y[ix];
                    float4 o;
                    o.x = acc[tt][4 * q]     + D0 * yv.x;
                    o.y = acc[tt][4 * q + 1] + D0 * yv.y;
                    o.z = acc[tt][4 * q + 2] + D0 * yv.z;
                    o.w = acc[tt][4 * q + 3] + D0 * yv.w;
                    *(float4*)&out[ix] = o;
                }
            }
        }
    }

#undef ROUND8
#undef REM4
#undef STEPE
#undef STEPO
#undef MFT
#undef LOADF
}

// ---------------- host ----------------

extern "C" void kernel_launch(void* const* d_in, const int* in_sizes, int n_in,
                              void* d_out, int out_size, void* d_ws, size_t ws_size,
                              hipStream_t stream) {
    const float* y  = (const float*)d_in[0];
    const float* A  = (const float*)d_in[1];
    const float* Bv = (const float*)d_in[2];
    const float* Cv = (const float*)d_in[3];
    const float* Dp = (const float*)d_in[4];
    float* out = (float*)d_out;
    char* w = (char*)d_ws;
    uint2* Rqg = (uint2*)w;                       // 36,864 B
    uint4* ybf = (uint4*)(w + 36864);             // 16,777,216 B (2048x4096 bf16)

    k_build<<<dim3(257), dim3(1024), 0, stream>>>(A, Bv, Cv, y, Rqg, ybf);
    k_conv<<<dim3(32, 16), dim3(256), 0, stream>>>(Rqg, ybf, y, Dp, out);

    (void)in_sizes; (void)n_in; (void)out_size; (void)ws_size;
}

// Round 20
// 69.761 us; speedup vs baseline: 1.1590x; 1.1590x over previous
//
#include <hip/hip_runtime.h>

#define N_ 256
#define L_ 4096
#define DM_ 2048
#define STEPF (1.0f / 4096.0f)
#define NW 10
#define NV 5
#define RQN 4608

typedef short bf16x8 __attribute__((ext_vector_type(8)));
typedef float f32x4 __attribute__((ext_vector_type(4)));
typedef unsigned int uint32;

__device__ __forceinline__ uint32 bf16rne(float f) {
    uint32 u = __builtin_bit_cast(uint32, f);
    return (u + 0x7FFFu + ((u >> 16) & 1u)) >> 16;
}
__device__ __forceinline__ float rdlane(float v, int l) {
    return __builtin_bit_cast(float, __builtin_amdgcn_readlane(__builtin_bit_cast(int, v), l));
}
__device__ __forceinline__ float hif(float x) {
    return __builtin_bit_cast(float, __builtin_bit_cast(uint32, x) & 0xFFFF0000u);
}
#define PK2(LO, HI) __builtin_amdgcn_perm(__builtin_bit_cast(uint32, (HI)), \
                                          __builtin_bit_cast(uint32, (LO)), 0x07060302u)

// ---------------- Phase 1: build K (block 0) + pack y->bf16 (blocks 1..256) ----------------
// (bit-identical to R17's kernel)
__global__ __launch_bounds__(1024) void k_build(const float* __restrict__ Araw,
                                                const float* __restrict__ Bv,
                                                const float* __restrict__ Cv,
                                                const float* __restrict__ yf,
                                                uint2* __restrict__ Rqg,
                                                uint4* __restrict__ ybf) {
    const int tid = threadIdx.x;
    if (blockIdx.x > 0) {
        const size_t base = (size_t)(blockIdx.x - 1) * 32768;
        const float4* yin = (const float4*)(yf + base);
        uint4* yo = ybf + base / 8;
#pragma unroll
        for (int i = 0; i < 4; ++i) {
            int c = i * 1024 + tid;
            float4 q0 = yin[2 * c], q1 = yin[2 * c + 1];
            uint4 o; o.x = PK2(q0.x, q0.y); o.y = PK2(q0.z, q0.w);
                     o.z = PK2(q1.x, q1.y); o.w = PK2(q1.z, q1.w);
            yo[c] = o;
        }
        return;
    }

    __shared__ float sm[39168];
    float* kry = sm;
    float* red = sm + 3840;
    float* Wl  = sm + 5888;
    float* Vt  = sm + 22528;
    float* Kf  = sm;

    const int j = tid & 255, seg = tid >> 8, lane = tid & 63;
    const int e = 64 * seg + lane;
    float a[64];

#define DOT64(S0, S1, VV) { \
    _Pragma("unroll") \
    for (int m = 0; m < 64; m += 2) { \
        S0 = fmaf(rdlane(VV, m), a[m], S0); \
        S1 = fmaf(rdlane(VV, m + 1), a[m + 1], S1); \
    } }

#pragma unroll
    for (int m = 0; m < 64; ++m) a[m] = Araw[(64 * seg + m) * 256 + j];
    if (tid < 256) kry[tid] = Cv[tid];
    __syncthreads();
    const float WSC = 4032.0f / 4096.0f;
    {
        float vv = kry[e];
        for (int n = 1; n < NW; ++n) {
            float s0 = 0.f, s1 = 0.f;
            DOT64(s0, s1, vv)
            float* rb = red + (n & 1) * 1024;
            rb[seg * 256 + j] = s0 + s1;
            __syncthreads();
            float sc = WSC / (float)n;
            vv = (rb[e] + rb[256 + e] + rb[512 + e] + rb[768 + e]) * sc;
            if (tid < 256)
                kry[n * 256 + tid] = (rb[tid] + rb[256 + tid] + rb[512 + tid] + rb[768 + tid]) * sc;
        }
    }
    __syncthreads();
    {
        float kj[NW];
#pragma unroll
        for (int n = 0; n < NW; ++n) kj[n] = kry[n * 256 + j];
#pragma unroll
        for (int u = 0; u < 16; ++u) {
            int q = seg + 4 * u;
            float c = (float)q * (1.0f / 63.0f);
            float h = kj[NW - 1];
#pragma unroll
            for (int n = NW - 2; n >= 0; --n) h = fmaf(c, h, kj[n]);
            Wl[q * 260 + j] = h;
        }
    }
    {
        const float4* Ar = (const float4*)(Araw + (size_t)j * 256 + 64 * seg);
#pragma unroll
        for (int m4 = 0; m4 < 16; ++m4) {
            float4 q4 = Ar[m4];
            a[4 * m4] = q4.x; a[4 * m4 + 1] = q4.y; a[4 * m4 + 2] = q4.z; a[4 * m4 + 3] = q4.w;
        }
    }
    const float ms = 0.5f * STEPF;
    const float bve = Bv[e];
    {
        float vv = bve;
        for (int it = 0; it < 2; ++it) {
            float s0 = 0.f, s1 = 0.f;
            DOT64(s0, s1, vv)
            float* rb = red + (it & 1) * 1024;
            rb[seg * 256 + j] = s0 + s1;
            __syncthreads();
            vv = fmaf(ms, rb[e] + rb[256 + e] + rb[512 + e] + rb[768 + e], bve);
            if (it == 1 && tid < 256) {
                float su = rb[tid] + rb[256 + tid] + rb[512 + tid] + rb[768 + tid];
                kry[tid] = STEPF * fmaf(ms, su, Bv[tid]);
            }
        }
    }
    __syncthreads();
    const float VSC = 63.0f / 4096.0f;
    {
        float vv = kry[e];
        for (int n = 1; n < NV; ++n) {
            float s0 = 0.f, s1 = 0.f;
            DOT64(s0, s1, vv)
            float* rb = red + (n & 1) * 1024;
            rb[seg * 256 + j] = s0 + s1;
            __syncthreads();
            float sc = VSC / (float)n;
            vv = (rb[e] + rb[256 + e] + rb[512 + e] + rb[768 + e]) * sc;
            if (tid < 256)
                kry[n * 256 + tid] = (rb[tid] + rb[256 + tid] + rb[512 + tid] + rb[768 + tid]) * sc;
        }
    }
    __syncthreads();
    {
        float kj[NV];
#pragma unroll
        for (int n = 0; n < NV; ++n) kj[n] = kry[n * 256 + j];
#pragma unroll
        for (int u = 0; u < 16; ++u) {
            int r = seg + 4 * u;
            float c = (float)r * (1.0f / 63.0f);
            float h = kj[NV - 1];
#pragma unroll
            for (int n = NV - 2; n >= 0; --n) h = fmaf(c, h, kj[n]);
            Vt[r * 260 + j] = h;
        }
    }
    __syncthreads();
    {
        const int wv = tid >> 6;
        const int qt = wv >> 2, rt = wv & 3;
        const int n16 = lane & 15, g4 = lane >> 4;
        const int q = 16 * qt + n16;
        const int r = 16 * rt + n16;
        f32x4 ac = (f32x4){0.f, 0.f, 0.f, 0.f};
        for (int s = 0; s < 8; ++s) {
            const int kk = 32 * s + 8 * g4;
            float4 w0 = *(const float4*)&Wl[q * 260 + kk];
            float4 w1 = *(const float4*)&Wl[q * 260 + kk + 4];
            float4 v0 = *(const float4*)&Vt[r * 260 + kk];
            float4 v1 = *(const float4*)&Vt[r * 260 + kk + 4];
            uint4 uh; uh.x = PK2(w0.x, w0.y); uh.y = PK2(w0.z, w0.w);
                      uh.z = PK2(w1.x, w1.y); uh.w = PK2(w1.z, w1.w);
            float l0 = w0.x - hif(w0.x), l1 = w0.y - hif(w0.y);
            float l2 = w0.z - hif(w0.z), l3 = w0.w - hif(w0.w);
            float l4 = w1.x - hif(w1.x), l5 = w1.y - hif(w1.y);
            float l6 = w1.z - hif(w1.z), l7 = w1.w - hif(w1.w);
            uint4 ul; ul.x = PK2(l0, l1); ul.y = PK2(l2, l3);
                      ul.z = PK2(l4, l5); ul.w = PK2(l6, l7);
            uint4 uv; uv.x = PK2(v0.x, v0.y); uv.y = PK2(v0.z, v0.w);
                      uv.z = PK2(v1.x, v1.y); uv.w = PK2(v1.z, v1.w);
            ac = __builtin_amdgcn_mfma_f32_16x16x32_bf16(__builtin_bit_cast(bf16x8, uh),
                                                         __builtin_bit_cast(bf16x8, uv), ac, 0, 0, 0);
            ac = __builtin_amdgcn_mfma_f32_16x16x32_bf16(__builtin_bit_cast(bf16x8, ul),
                                                         __builtin_bit_cast(bf16x8, uv), ac, 0, 0, 0);
        }
#pragma unroll
        for (int jj = 0; jj < 4; ++jj)
            Kf[(16 * qt + 4 * g4 + jj) * 64 + r] = ac[jj];
    }
    __syncthreads();
    for (int i = tid; i < RQN; i += 1024) {
        int aa = 4095 - i;
        uint32 e0 = (aa >= 0) ? bf16rne(Kf[aa]) : 0u;
        uint32 e1 = (aa >= 1) ? bf16rne(Kf[aa - 1]) : 0u;
        uint32 e2 = (aa >= 2) ? bf16rne(Kf[aa - 2]) : 0u;
        uint32 e3 = (aa >= 3) ? bf16rne(Kf[aa - 3]) : 0u;
        uint2 v; v.x = e0 | (e1 << 16); v.y = e2 | (e3 << 16);
        Rqg[i] = v;
    }
#undef DOT64
}

// ---------------- Phase 2: MFMA causal conv, T=16, depth-4 y prefetch ----------------
// R17 structure; single change: y prefetch deepened 2->4 rotating uint4 buffers
// (statically unrolled).  Cross-round fit: step cost = ~390 fixed + 15/MFMA; the 390
// matches depth-2 load-latency equilibrium (lat/2).  Depth 4 -> lat/4 ~ 200.
__global__ __launch_bounds__(256, 2) void k_conv(const uint2* __restrict__ Rqg,
                                                 const uint4* __restrict__ ybf,
                                                 const float* __restrict__ y,
                                                 const float* __restrict__ Dp,
                                                 float* __restrict__ out) {
    __shared__ uint2 Rq[RQN];
    __shared__ f32x4 mbuf[2][8][64];
    const int tid = threadIdx.x;
#pragma unroll
    for (int i = 0; i < RQN / 256; ++i) Rq[i * 256 + tid] = Rqg[i * 256 + tid];
    __syncthreads();

    const int w = tid >> 6, lane = tid & 63;
    const int n = lane & 15, g = lane >> 4;
    const int ds = w & 1, jh = w >> 1;
    const int by = (int)blockIdx.y;                   // 0..7
    const int d0w = (int)blockIdx.x * 32 + ds * 16;
    const int d = d0w + n;
    const uint4* __restrict__ ybr = ybf + (size_t)d * (L_ / 8);   // 512 uint4 per row
    const float D0 = Dp[0];

#define LOADF(SL, I0) { \
    uint2 u0 = Rq[(I0)]; uint2 u1 = Rq[(I0) + 4]; \
    uint4 uu; uu.x = u0.x; uu.y = u0.y; uu.z = u1.x; uu.w = u1.y; \
    fr[SL] = __builtin_bit_cast(bf16x8, uu); }
#define MF(TI, SL) acc[TI] = __builtin_amdgcn_mfma_f32_16x16x32_bf16(av, fr[SL], acc[TI], 0, 0, 0);

// One step: consume buffer AV (loaded 4 steps ago), refill it for step +4.
#define STEPB(AV, S0,S1,S2,S3,S4,S5,S6,S7,S8,S9,S10,S11,S12,S13,S14,S15) { \
    av = __builtin_bit_cast(bf16x8, AV); \
    MF(14, S14) MF(15, S15) \
    LOADF(S14, bcur + 32) LOADF(S15, bcur + 16) \
    AV = ybr[yn & 511]; \
    yn += 4; bcur += 32; \
    MF(0,S0) MF(1,S1) MF(2,S2) MF(3,S3) MF(4,S4) MF(5,S5) MF(6,S6) MF(7,S7) \
    MF(8,S8) MF(9,S9) MF(10,S10) MF(11,S11) MF(12,S12) MF(13,S13) \
}

#define ROUND8() \
    STEPB(av0, 0,1,2,3,4,5,6,7,8,9,10,11,12,13,14,15) \
    STEPB(av1, 14,15,0,1,2,3,4,5,6,7,8,9,10,11,12,13) \
    STEPB(av2, 12,13,14,15,0,1,2,3,4,5,6,7,8,9,10,11) \
    STEPB(av3, 10,11,12,13,14,15,0,1,2,3,4,5,6,7,8,9) \
    STEPB(av0, 8,9,10,11,12,13,14,15,0,1,2,3,4,5,6,7) \
    STEPB(av1, 6,7,8,9,10,11,12,13,14,15,0,1,2,3,4,5) \
    STEPB(av2, 4,5,6,7,8,9,10,11,12,13,14,15,0,1,2,3) \
    STEPB(av3, 2,3,4,5,6,7,8,9,10,11,12,13,14,15,0,1)

#define ROUND4() \
    STEPB(av0, 0,1,2,3,4,5,6,7,8,9,10,11,12,13,14,15) \
    STEPB(av1, 14,15,0,1,2,3,4,5,6,7,8,9,10,11,12,13) \
    STEPB(av2, 12,13,14,15,0,1,2,3,4,5,6,7,8,9,10,11) \
    STEPB(av3, 10,11,12,13,14,15,0,1,2,3,4,5,6,7,8,9)

    for (int strip = 0; strip < 2; ++strip) {
        const int v = strip ? by : (15 - by);
        const int t0 = v << 8;
        const int Sh = 4 * (v + 1);       // per-wave j-steps (half of strip total)
        const int s0 = jh * Sh;           // starting j-chunk

        f32x4 acc[16];
#pragma unroll
        for (int i = 0; i < 16; ++i) acc[i] = (f32x4){0.f, 0.f, 0.f, 0.f};
        bf16x8 fr[16], av;
        uint4 av0, av1, av2, av3;

        const int B0 = 4095 - t0 - n + 8 * g + 32 * s0;
#pragma unroll
        for (int ti = 0; ti < 16; ++ti) LOADF(ti, B0 - 16 * ti)
        av0 = ybr[4 * s0 + g];            // step s0   (max idx 271 < 512)
        av1 = ybr[4 * s0 + 4 + g];        // step s0+1
        av2 = ybr[4 * s0 + 8 + g];        // step s0+2
        av3 = ybr[4 * s0 + 12 + g];       // step s0+3
        int bcur = B0;
        int yn = 4 * s0 + 16 + g;         // uint4 index of y prefetch, 4 steps ahead

        const int n8 = Sh >> 3;
        for (int it = 0; it < n8; ++it) {
            ROUND8()
        }
        if (Sh & 4) {
            ROUND4()
        }

        // ---- merge j-halves (2 conflict-free LDS rounds), then jh=0 stores ----
#pragma unroll
        for (int rr = 0; rr < 2; ++rr) {
            if (jh == 1) {
#pragma unroll
                for (int i = 0; i < 8; ++i) mbuf[ds][i][lane] = acc[rr * 8 + i];
            }
            __syncthreads();
            if (jh == 0) {
#pragma unroll
                for (int i = 0; i < 8; ++i) {
                    f32x4 m = mbuf[ds][i][lane];
                    acc[rr * 8 + i][0] += m[0]; acc[rr * 8 + i][1] += m[1];
                    acc[rr * 8 + i][2] += m[2]; acc[rr * 8 + i][3] += m[3];
                }
            }
            __syncthreads();
        }
        if (jh == 0) {
#pragma unroll
            for (int ti = 0; ti < 16; ++ti) {
                int tcol = t0 + 16 * ti + n;
#pragma unroll
                for (int r = 0; r < 4; ++r) {
                    int dr = d0w + 4 * g + r;
                    size_t ix = (size_t)dr * L_ + tcol;
                    out[ix] = acc[ti][r] + D0 * y[ix];   // D-term stays f32
                }
            }
        }
    }

#undef ROUND8
#undef ROUND4
#undef STEPB
#undef MF
#undef LOADF
}

// ---------------- host ----------------

extern "C" void kernel_launch(void* const* d_in, const int* in_sizes, int n_in,
                              void* d_out, int out_size, void* d_ws, size_t ws_size,
                              hipStream_t stream) {
    const float* y  = (const float*)d_in[0];
    const float* A  = (const float*)d_in[1];
    const float* Bv = (const float*)d_in[2];
    const float* Cv = (const float*)d_in[3];
    const float* Dp = (const float*)d_in[4];
    float* out = (float*)d_out;
    char* w = (char*)d_ws;
    uint2* Rqg = (uint2*)w;                       // 36,864 B
    uint4* ybf = (uint4*)(w + 36864);             // 16,777,216 B (2048x4096 bf16)

    k_build<<<dim3(257), dim3(1024), 0, stream>>>(A, Bv, Cv, y, Rqg, ybf);
    k_conv<<<dim3(64, 8), dim3(256), 0, stream>>>(Rqg, ybf, y, Dp, out);

    (void)in_sizes; (void)n_in; (void)out_size; (void)ws_size;
}

// Round 21
// 64.758 us; speedup vs baseline: 1.2485x; 1.0773x over previous
//
#include <hip/hip_runtime.h>

#define N_ 256
#define L_ 4096
#define DM_ 2048
#define STEPF (1.0f / 4096.0f)
#define NW 10
#define NV 5
#define RBN 4608
#define KSC 131072.0f          // 2^17 folded into fp8 K
#define KSCI 7.62939453125e-06f // 2^-17

typedef short bf16x8 __attribute__((ext_vector_type(8)));
typedef int i32x8 __attribute__((ext_vector_type(8)));
typedef float f32x4 __attribute__((ext_vector_type(4)));
typedef float f32x16 __attribute__((ext_vector_type(16)));
typedef unsigned int uint32;

__device__ __forceinline__ float rdlane(float v, int l) {
    return __builtin_bit_cast(float, __builtin_amdgcn_readlane(__builtin_bit_cast(int, v), l));
}
__device__ __forceinline__ float hif(float x) {
    return __builtin_bit_cast(float, __builtin_bit_cast(uint32, x) & 0xFFFF0000u);
}
#define PK2(LO, HI) __builtin_amdgcn_perm(__builtin_bit_cast(uint32, (HI)), \
                                          __builtin_bit_cast(uint32, (LO)), 0x07060302u)
// pack 4 f32 -> 4 fp8 e4m3 bytes
__device__ __forceinline__ int pk4f8(float a, float b, float c, float d) {
    int r = __builtin_amdgcn_cvt_pk_fp8_f32(a, b, 0, false);
    r = __builtin_amdgcn_cvt_pk_fp8_f32(c, d, r, true);
    return r;
}

// ---------------- Phase 1: build K (block 0) + pack y->fp8 (blocks 1..256) ----------------
__global__ __launch_bounds__(1024) void k_build(const float* __restrict__ Araw,
                                                const float* __restrict__ Bv,
                                                const float* __restrict__ Cv,
                                                const float* __restrict__ yf,
                                                uint2* __restrict__ Rb8g,
                                                uint4* __restrict__ yf8) {
    const int tid = threadIdx.x;
    if (blockIdx.x > 0) {
        // y -> fp8: each thread emits one 32-byte chunk (2 uint4), reads 8 float4.
        const size_t co = (size_t)(blockIdx.x - 1) * 1024 + tid;   // 32-elem chunk id
        const float4* yin = (const float4*)(yf + co * 32);
        float4 q[8];
#pragma unroll
        for (int i = 0; i < 8; ++i) q[i] = yin[i];
        uint4 o0, o1;
        o0.x = pk4f8(q[0].x, q[0].y, q[0].z, q[0].w);
        o0.y = pk4f8(q[1].x, q[1].y, q[1].z, q[1].w);
        o0.z = pk4f8(q[2].x, q[2].y, q[2].z, q[2].w);
        o0.w = pk4f8(q[3].x, q[3].y, q[3].z, q[3].w);
        o1.x = pk4f8(q[4].x, q[4].y, q[4].z, q[4].w);
        o1.y = pk4f8(q[5].x, q[5].y, q[5].z, q[5].w);
        o1.z = pk4f8(q[6].x, q[6].y, q[6].z, q[6].w);
        o1.w = pk4f8(q[7].x, q[7].y, q[7].z, q[7].w);
        yf8[2 * co] = o0;
        yf8[2 * co + 1] = o1;
        return;
    }

    __shared__ float sm[39168];
    float* kry = sm;
    float* red = sm + 3840;
    float* Wl  = sm + 5888;
    float* Vt  = sm + 22528;
    float* Kf  = sm;

    const int j = tid & 255, seg = tid >> 8, lane = tid & 63;
    const int e = 64 * seg + lane;
    float a[64];

#define DOT64(S0, S1, VV) { \
    _Pragma("unroll") \
    for (int m = 0; m < 64; m += 2) { \
        S0 = fmaf(rdlane(VV, m), a[m], S0); \
        S1 = fmaf(rdlane(VV, m + 1), a[m + 1], S1); \
    } }

#pragma unroll
    for (int m = 0; m < 64; ++m) a[m] = Araw[(64 * seg + m) * 256 + j];
    if (tid < 256) kry[tid] = Cv[tid];
    __syncthreads();
    const float WSC = 4032.0f / 4096.0f;
    {
        float vv = kry[e];
        for (int n = 1; n < NW; ++n) {
            float s0 = 0.f, s1 = 0.f;
            DOT64(s0, s1, vv)
            float* rb = red + (n & 1) * 1024;
            rb[seg * 256 + j] = s0 + s1;
            __syncthreads();
            float sc = WSC / (float)n;
            vv = (rb[e] + rb[256 + e] + rb[512 + e] + rb[768 + e]) * sc;
            if (tid < 256)
                kry[n * 256 + tid] = (rb[tid] + rb[256 + tid] + rb[512 + tid] + rb[768 + tid]) * sc;
        }
    }
    __syncthreads();
    {
        float kj[NW];
#pragma unroll
        for (int n = 0; n < NW; ++n) kj[n] = kry[n * 256 + j];
#pragma unroll
        for (int u = 0; u < 16; ++u) {
            int q = seg + 4 * u;
            float c = (float)q * (1.0f / 63.0f);
            float h = kj[NW - 1];
#pragma unroll
            for (int n = NW - 2; n >= 0; --n) h = fmaf(c, h, kj[n]);
            Wl[q * 260 + j] = h;
        }
    }
    {
        const float4* Ar = (const float4*)(Araw + (size_t)j * 256 + 64 * seg);
#pragma unroll
        for (int m4 = 0; m4 < 16; ++m4) {
            float4 q4 = Ar[m4];
            a[4 * m4] = q4.x; a[4 * m4 + 1] = q4.y; a[4 * m4 + 2] = q4.z; a[4 * m4 + 3] = q4.w;
        }
    }
    const float ms = 0.5f * STEPF;
    const float bve = Bv[e];
    {
        float vv = bve;
        for (int it = 0; it < 2; ++it) {
            float s0 = 0.f, s1 = 0.f;
            DOT64(s0, s1, vv)
            float* rb = red + (it & 1) * 1024;
            rb[seg * 256 + j] = s0 + s1;
            __syncthreads();
            vv = fmaf(ms, rb[e] + rb[256 + e] + rb[512 + e] + rb[768 + e], bve);
            if (it == 1 && tid < 256) {
                float su = rb[tid] + rb[256 + tid] + rb[512 + tid] + rb[768 + tid];
                kry[tid] = STEPF * fmaf(ms, su, Bv[tid]);
            }
        }
    }
    __syncthreads();
    const float VSC = 63.0f / 4096.0f;
    {
        float vv = kry[e];
        for (int n = 1; n < NV; ++n) {
            float s0 = 0.f, s1 = 0.f;
            DOT64(s0, s1, vv)
            float* rb = red + (n & 1) * 1024;
            rb[seg * 256 + j] = s0 + s1;
            __syncthreads();
            float sc = VSC / (float)n;
            vv = (rb[e] + rb[256 + e] + rb[512 + e] + rb[768 + e]) * sc;
            if (tid < 256)
                kry[n * 256 + tid] = (rb[tid] + rb[256 + tid] + rb[512 + tid] + rb[768 + tid]) * sc;
        }
    }
    __syncthreads();
    {
        float kj[NV];
#pragma unroll
        for (int n = 0; n < NV; ++n) kj[n] = kry[n * 256 + j];
#pragma unroll
        for (int u = 0; u < 16; ++u) {
            int r = seg + 4 * u;
            float c = (float)r * (1.0f / 63.0f);
            float h = kj[NV - 1];
#pragma unroll
            for (int n = NV - 2; n >= 0; --n) h = fmaf(c, h, kj[n]);
            Vt[r * 260 + j] = h;
        }
    }
    __syncthreads();
    {
        const int wv = tid >> 6;
        const int qt = wv >> 2, rt = wv & 3;
        const int n16 = lane & 15, g4 = lane >> 4;
        const int q = 16 * qt + n16;
        const int r = 16 * rt + n16;
        f32x4 ac = (f32x4){0.f, 0.f, 0.f, 0.f};
        for (int s = 0; s < 8; ++s) {
            const int kk = 32 * s + 8 * g4;
            float4 w0 = *(const float4*)&Wl[q * 260 + kk];
            float4 w1 = *(const float4*)&Wl[q * 260 + kk + 4];
            float4 v0 = *(const float4*)&Vt[r * 260 + kk];
            float4 v1 = *(const float4*)&Vt[r * 260 + kk + 4];
            uint4 uh; uh.x = PK2(w0.x, w0.y); uh.y = PK2(w0.z, w0.w);
                      uh.z = PK2(w1.x, w1.y); uh.w = PK2(w1.z, w1.w);
            float l0 = w0.x - hif(w0.x), l1 = w0.y - hif(w0.y);
            float l2 = w0.z - hif(w0.z), l3 = w0.w - hif(w0.w);
            float l4 = w1.x - hif(w1.x), l5 = w1.y - hif(w1.y);
            float l6 = w1.z - hif(w1.z), l7 = w1.w - hif(w1.w);
            uint4 ul; ul.x = PK2(l0, l1); ul.y = PK2(l2, l3);
                      ul.z = PK2(l4, l5); ul.w = PK2(l6, l7);
            uint4 uv; uv.x = PK2(v0.x, v0.y); uv.y = PK2(v0.z, v0.w);
                      uv.z = PK2(v1.x, v1.y); uv.w = PK2(v1.z, v1.w);
            ac = __builtin_amdgcn_mfma_f32_16x16x32_bf16(__builtin_bit_cast(bf16x8, uh),
                                                         __builtin_bit_cast(bf16x8, uv), ac, 0, 0, 0);
            ac = __builtin_amdgcn_mfma_f32_16x16x32_bf16(__builtin_bit_cast(bf16x8, ul),
                                                         __builtin_bit_cast(bf16x8, uv), ac, 0, 0, 0);
        }
#pragma unroll
        for (int jj = 0; jj < 4; ++jj)
            Kf[(16 * qt + 4 * g4 + jj) * 64 + r] = ac[jj];
    }
    __syncthreads();

    // ---- pack reversed-K byte table: Rb8g[i] = fp8(K[4095-i-b]*2^17), b=0..7 ----
    for (int i = tid; i < RBN; i += 1024) {
        float v[8];
#pragma unroll
        for (int b = 0; b < 8; ++b) {
            int idx = 4095 - i - b;
            v[b] = (idx >= 0) ? Kf[idx] * KSC : 0.f;
        }
        uint2 o;
        o.x = (uint32)pk4f8(v[0], v[1], v[2], v[3]);
        o.y = (uint32)pk4f8(v[4], v[5], v[6], v[7]);
        Rb8g[i] = o;
    }
#undef DOT64
}

// ---------------- Phase 2: fp8-MX causal conv, mfma_scale 32x32x64 ----------------
// D[t][d] = sum_j K[t-j] y[j]: A = Toeplitz K (fp8, x2^17), B = y (fp8).
// Per step K=64: 4 MFMA, 2 new A-frags (lag-2 reuse), 8x ds_read_b64, 32B y.
// Strips 128 cols, pairs (31-by, by) -> 33 steps/wave const; j-split 2.
// Grid (32,16) = 512 blocks = 2/CU.  C/D layout = R19-validated 32x32 mapping.
__global__ __launch_bounds__(256, 2) void k_conv(const uint2* __restrict__ Rb8g,
                                                 const uint4* __restrict__ yf8,
                                                 const float* __restrict__ y,
                                                 const float* __restrict__ Dp,
                                                 float* __restrict__ out) {
    __shared__ uint2 Rb8[RBN];
    __shared__ f32x4 mbuf[2][8][64];
    const int tid = threadIdx.x;
#pragma unroll
    for (int i = 0; i < RBN / 256; ++i) Rb8[i * 256 + tid] = Rb8g[i * 256 + tid];
    __syncthreads();

    const int w = tid >> 6, lane = tid & 63;
    const int m32 = lane & 31, h = lane >> 5;
    const int ds = w & 1, jh = w >> 1;
    const int by = (int)blockIdx.y;                   // 0..15
    const int d0w = (int)blockIdx.x * 64 + ds * 32;
    const int d = d0w + m32;
    const uint4* __restrict__ yq8 = yf8 + (size_t)d * (L_ / 16);   // 256 uint4/row
    const float D0 = Dp[0];

#define LOADF8(SL, E) { \
    uint2 q0 = Rb8[(E)]; uint2 q1 = Rb8[(E) + 8]; uint2 q2 = Rb8[(E) + 16]; uint2 q3 = Rb8[(E) + 24]; \
    i32x8 f; f[0] = (int)q0.x; f[1] = (int)q0.y; f[2] = (int)q1.x; f[3] = (int)q1.y; \
    f[4] = (int)q2.x; f[5] = (int)q2.y; f[6] = (int)q3.x; f[7] = (int)q3.y; \
    fr[SL] = f; }
#define MKB(BA, BB) { \
    i32x8 f; f[0] = (int)(BA).x; f[1] = (int)(BA).y; f[2] = (int)(BA).z; f[3] = (int)(BA).w; \
    f[4] = (int)(BB).x; f[5] = (int)(BB).y; f[6] = (int)(BB).z; f[7] = (int)(BB).w; \
    bv = f; }
#define MFT(TT, SL) acc[TT] = __builtin_amdgcn_mfma_scale_f32_32x32x64_f8f6f4( \
    fr[SL], bv, acc[TT], 0, 0, 0, 0x7F7F7F7F, 0, 0x7F7F7F7F);

// Phase 0 (s even): tt->slots 0,1,2,3.  Consume tt=2,3, reload slots 2,3 (next step's
// tt=0,1 frags at bases bcur+64, bcur+32), then tt=0,1.  Phase 1: roles swapped.
#define STEPE() { \
    MKB(avea, aveb); \
    MFT(2, 2) MFT(3, 3) \
    LOADF8(2, bcur + 64) LOADF8(3, bcur + 32) \
    avea = yq8[yn & 255]; aveb = yq8[(yn + 1) & 255]; \
    yn += 4; bcur += 64; \
    MFT(0, 0) MFT(1, 1) \
}
#define STEPO() { \
    MKB(avoa, avob); \
    MFT(2, 0) MFT(3, 1) \
    LOADF8(0, bcur + 64) LOADF8(1, bcur + 32) \
    avoa = yq8[yn & 255]; avob = yq8[(yn + 1) & 255]; \
    yn += 4; bcur += 64; \
    MFT(0, 2) MFT(1, 3) \
}

    for (int strip = 0; strip < 2; ++strip) {
        const int v = strip ? by : (31 - by);
        const int t0 = v << 7;
        const int ShW = v + 1;            // per-wave K=64 steps (half of strip total)
        const int s0 = jh * ShW;

        f32x16 acc[4] = {};
        i32x8 fr[4], bv;
        uint4 avea, aveb, avoa, avob;

        const int B0 = 4095 - t0 - m32 + 32 * h + 64 * s0;
        LOADF8(0, B0) LOADF8(1, B0 - 32) LOADF8(2, B0 - 64) LOADF8(3, B0 - 96)
        avea = yq8[(4 * s0 + 2 * h) & 255];     aveb = yq8[(4 * s0 + 2 * h + 1) & 255];
        avoa = yq8[(4 * s0 + 4 + 2 * h) & 255]; avob = yq8[(4 * s0 + 5 + 2 * h) & 255];
        int bcur = B0;
        int yn = 4 * s0 + 8 + 2 * h;

        const int nr = ShW >> 1;
        for (int it = 0; it < nr; ++it) {
            STEPE()
            STEPO()
        }
        if (ShW & 1) {
            STEPE()
        }

        // ---- merge j-halves (2 LDS rounds of 2 tiles), then jh=0 stores ----
#pragma unroll
        for (int rr = 0; rr < 2; ++rr) {
            if (jh == 1) {
#pragma unroll
                for (int tp = 0; tp < 2; ++tp)
#pragma unroll
                    for (int c = 0; c < 4; ++c) {
                        f32x4 ch = {acc[2 * rr + tp][4 * c], acc[2 * rr + tp][4 * c + 1],
                                    acc[2 * rr + tp][4 * c + 2], acc[2 * rr + tp][4 * c + 3]};
                        mbuf[ds][4 * tp + c][lane] = ch;
                    }
            }
            __syncthreads();
            if (jh == 0) {
#pragma unroll
                for (int tp = 0; tp < 2; ++tp)
#pragma unroll
                    for (int c = 0; c < 4; ++c) {
                        f32x4 mm = mbuf[ds][4 * tp + c][lane];
                        acc[2 * rr + tp][4 * c]     += mm[0];
                        acc[2 * rr + tp][4 * c + 1] += mm[1];
                        acc[2 * rr + tp][4 * c + 2] += mm[2];
                        acc[2 * rr + tp][4 * c + 3] += mm[3];
                    }
            }
            __syncthreads();
        }
        if (jh == 0) {
            // C/D (R19-validated): col = lane&31 -> d; row = (r&3) + 8*(r>>2) + 4*h.
#pragma unroll
            for (int tt = 0; tt < 4; ++tt) {
#pragma unroll
                for (int q = 0; q < 4; ++q) {
                    int tb = t0 + 32 * tt + 8 * q + 4 * h;
                    size_t ix = (size_t)d * L_ + tb;
                    float4 yv = *(const float4*)&y[ix];
                    float4 o;
                    o.x = acc[tt][4 * q]     * KSCI + D0 * yv.x;
                    o.y = acc[tt][4 * q + 1] * KSCI + D0 * yv.y;
                    o.z = acc[tt][4 * q + 2] * KSCI + D0 * yv.z;
                    o.w = acc[tt][4 * q + 3] * KSCI + D0 * yv.w;
                    *(float4*)&out[ix] = o;
                }
            }
        }
    }

#undef STEPE
#undef STEPO
#undef MFT
#undef MKB
#undef LOADF8
}

// ---------------- host ----------------

extern "C" void kernel_launch(void* const* d_in, const int* in_sizes, int n_in,
                              void* d_out, int out_size, void* d_ws, size_t ws_size,
                              hipStream_t stream) {
    const float* y  = (const float*)d_in[0];
    const float* A  = (const float*)d_in[1];
    const float* Bv = (const float*)d_in[2];
    const float* Cv = (const float*)d_in[3];
    const float* Dp = (const float*)d_in[4];
    float* out = (float*)d_out;
    char* w = (char*)d_ws;
    uint2* Rb8g = (uint2*)w;                      // 36,864 B (fp8 rev-K byte table)
    uint4* yf8  = (uint4*)(w + 36864);            // 8,388,608 B (2048x4096 fp8)

    k_build<<<dim3(257), dim3(1024), 0, stream>>>(A, Bv, Cv, y, Rb8g, yf8);
    k_conv<<<dim3(32, 16), dim3(256), 0, stream>>>(Rb8g, yf8, y, Dp, out);

    (void)in_sizes; (void)n_in; (void)out_size; (void)ws_size;
}